// Round 1
// baseline (104.982 us; speedup 1.0000x reference)
//
#include <hip/hip_runtime.h>
#include <math.h>

// ---------------- constants (match reference, f32-cast like np.float32) -----
namespace {
constexpr float DTf     = 0.01f;
constexpr float GAMMA_F = 0.103f;
constexpr float DRIVE   = 0.1f;
constexpr float COUPLE  = 0.1f;
constexpr float DAMP    = 0.01f;
constexpr float ENTRAIN = 0.1f;
constexpr float EXT_SC  = 0.1f;

constexpr double PHI    = 1.618033988749895;
constexpr double TWO_PI = 6.283185307179586476925287;
constexpr double PHI2   = PHI * PHI;
constexpr double PHI4   = PHI2 * PHI2;
constexpr double PHI5   = PHI4 * PHI;
constexpr double PHI7   = PHI5 * PHI2;
constexpr double PHI11  = PHI7 * PHI4;

constexpr float OMEGA_D = (float)(TWO_PI / (40.0 * PHI11));
constexpr float OMEGA_T = (float)(TWO_PI / (40.0 * PHI7));
constexpr float OMEGA_Q = (float)(TWO_PI / (40.0 * PHI5));
// dphase = DT * omega, computed in f32 like the reference
constexpr float DT_OM_D = DTf * OMEGA_D;
constexpr float DT_OM_T = DTf * OMEGA_T;
constexpr float DT_OM_Q = DTf * OMEGA_Q;
}

// load n4 float4s from s (16B-aligned) into flat float array d
__device__ __forceinline__ void ldf4(float* d, const float* s, int n4) {
#pragma unroll
    for (int i = 0; i < 4; ++i) {
        if (i < n4) {
            float4 v = ((const float4*)s)[i];
            d[4 * i + 0] = v.x; d[4 * i + 1] = v.y;
            d[4 * i + 2] = v.z; d[4 * i + 3] = v.w;
        }
    }
}

// One row of the GenesisHemisphere update. o[0..9] = {d0,d1,t0,t1,t2,q0..q3,mean_phase}
__device__ __forceinline__ void row_compute(
    float e,
    const float* dzr, const float* dpr,
    const float* tzr, const float* tpr,
    const float* qzr, const float* qpr,
    const float* Tm, const float* Qm, float tqc,
    float* o)
{
    const float ex = EXT_SC * e;

    // ---- D module (master clock, unbounded). Precise trig: feeds atan2. ----
    const float dpn0 = dpr[0] + DT_OM_D;
    const float dpn1 = dpr[1] + DT_OM_D;
    const float s0 = sinf(dpn0), c0 = cosf(dpn0);
    const float s1 = sinf(dpn1), c1 = cosf(dpn1);
    const float mp = atan2f(0.5f * (s0 + s1), 0.5f * (c0 + c1));

    o[0] = dzr[0] + DTf * (DRIVE * s0 + COUPLE * (dzr[1] + ex) - DAMP * dzr[0]);
    o[1] = dzr[1] + DTf * (DRIVE * s1 + COUPLE * (dzr[0] + ex) - DAMP * dzr[1]);

    // ---- T module: coupling matvec + entrainment toward mp, clamp GAMMA ----
    float to[3];
#pragma unroll
    for (int i = 0; i < 3; ++i) {
        const float nb = Tm[3 * i + 0] * tzr[0] + Tm[3 * i + 1] * tzr[1]
                       + Tm[3 * i + 2] * tzr[2] + ex;
        const float pn = tpr[i] + (DT_OM_T + ENTRAIN * __sinf(mp - tpr[i]));
        float v = tzr[i] + DTf * (DRIVE * __sinf(pn) + COUPLE * nb - DAMP * tzr[i]);
        v = fminf(fmaxf(v, -GAMMA_F), GAMMA_F);
        to[i] = v;
        o[2 + i] = v;
    }

    // ---- Q module: driven by mean T output * tq_coupling ----
    const float exq = EXT_SC * ((to[0] + to[1] + to[2]) * (1.0f / 3.0f) * tqc);
#pragma unroll
    for (int i = 0; i < 4; ++i) {
        const float nb = Qm[4 * i + 0] * qzr[0] + Qm[4 * i + 1] * qzr[1]
                       + Qm[4 * i + 2] * qzr[2] + Qm[4 * i + 3] * qzr[3] + exq;
        const float pn = qpr[i] + (DT_OM_Q + ENTRAIN * __sinf(mp - qpr[i]));
        float v = qzr[i] + DTf * (DRIVE * __sinf(pn) + COUPLE * nb - DAMP * qzr[i]);
        v = fminf(fmaxf(v, -GAMMA_F), GAMMA_F);
        o[5 + i] = v;
    }

    o[9] = mp;
}

__global__ __launch_bounds__(256) void genesis_kernel(
    const float* __restrict__ ext,
    const float* __restrict__ dz,
    const float* __restrict__ dp,
    const float* __restrict__ tz,
    const float* __restrict__ tp,
    const float* __restrict__ qz,
    const float* __restrict__ qp,
    const float* __restrict__ tcm,
    const float* __restrict__ qcm,
    const float* __restrict__ tqs,
    float* __restrict__ out,
    int B)
{
    // wave-uniform tiny matrices; L1-cached broadcast loads (likely s_load)
    float Tm[9], Qm[16];
#pragma unroll
    for (int i = 0; i < 9; ++i) Tm[i] = tcm[i];
#pragma unroll
    for (int i = 0; i < 16; ++i) Qm[i] = qcm[i];
    const float tqc = tqs[0];

    const int g = blockIdx.x * 256 + threadIdx.x;   // group of 4 rows
    const int nFull = B >> 2;

    if (g < nFull) {
        float ev[4], dzv[8], dpv[8], tzv[12], tpv[12], qzv[16], qpv[16];
        ldf4(ev,  ext + 4 * g,  1);
        ldf4(dzv, dz + 8 * g,   2);
        ldf4(dpv, dp + 8 * g,   2);
        ldf4(tzv, tz + 12 * g,  3);
        ldf4(tpv, tp + 12 * g,  3);
        ldf4(qzv, qz + 16 * g,  4);
        ldf4(qpv, qp + 16 * g,  4);

        float o[40];
#pragma unroll
        for (int r = 0; r < 4; ++r) {
            row_compute(ev[r], dzv + 2 * r, dpv + 2 * r,
                        tzv + 3 * r, tpv + 3 * r,
                        qzv + 4 * r, qpv + 4 * r,
                        Tm, Qm, tqc, o + 10 * r);
        }

#pragma unroll
        for (int j = 0; j < 10; ++j) {
            ((float4*)out)[10 * g + j] =
                make_float4(o[4 * j], o[4 * j + 1], o[4 * j + 2], o[4 * j + 3]);
        }
    } else if (g == nFull && (B & 3)) {
        // tail rows, scalar path
        const int rem = B & 3;
        for (int r = 0; r < rem; ++r) {
            const int b = 4 * nFull + r;
            float o[10];
            row_compute(ext[b], dz + 2 * b, dp + 2 * b,
                        tz + 3 * b, tp + 3 * b,
                        qz + 4 * b, qp + 4 * b,
                        Tm, Qm, tqc, o);
            for (int k = 0; k < 10; ++k) out[10 * b + k] = o[k];
        }
    }
}

extern "C" void kernel_launch(void* const* d_in, const int* in_sizes, int n_in,
                              void* d_out, int out_size, void* d_ws, size_t ws_size,
                              hipStream_t stream)
{
    const float* ext = (const float*)d_in[0];
    const float* dz  = (const float*)d_in[1];
    const float* dp  = (const float*)d_in[2];
    const float* tz  = (const float*)d_in[3];
    const float* tp  = (const float*)d_in[4];
    const float* qz  = (const float*)d_in[5];
    const float* qp  = (const float*)d_in[6];
    const float* tcm = (const float*)d_in[7];
    const float* qcm = (const float*)d_in[8];
    const float* tqs = (const float*)d_in[9];

    const int B = in_sizes[0];
    const int threads_needed = (B >> 2) + ((B & 3) ? 1 : 0);
    int grid = (threads_needed + 255) / 256;
    if (grid < 1) grid = 1;

    genesis_kernel<<<grid, 256, 0, stream>>>(ext, dz, dp, tz, tp, qz, qp,
                                             tcm, qcm, tqs,
                                             (float*)d_out, B);
}

// Round 2
// 89.125 us; speedup vs baseline: 1.1779x; 1.1779x over previous
//
#include <hip/hip_runtime.h>
#include <math.h>

// ---------------- constants (match reference, f32-cast like np.float32) -----
namespace {
constexpr float DTf     = 0.01f;
constexpr float GAMMA_F = 0.103f;
constexpr float DRIVE   = 0.1f;
constexpr float COUPLE  = 0.1f;
constexpr float DAMP    = 0.01f;
constexpr float ENTRAIN = 0.1f;
constexpr float EXT_SC  = 0.1f;

constexpr double PHI    = 1.618033988749895;
constexpr double TWO_PI = 6.283185307179586476925287;
constexpr double PHI2   = PHI * PHI;
constexpr double PHI4   = PHI2 * PHI2;
constexpr double PHI5   = PHI4 * PHI;
constexpr double PHI7   = PHI5 * PHI2;
constexpr double PHI11  = PHI7 * PHI4;

constexpr float OMEGA_D = (float)(TWO_PI / (40.0 * PHI11));
constexpr float OMEGA_T = (float)(TWO_PI / (40.0 * PHI7));
constexpr float OMEGA_Q = (float)(TWO_PI / (40.0 * PHI5));
constexpr float DT_OM_D = DTf * OMEGA_D;
constexpr float DT_OM_T = DTf * OMEGA_T;
constexpr float DT_OM_Q = DTf * OMEGA_Q;

constexpr int BLOCK = 256;
constexpr int OPAD  = 11;   // padded floats per row in LDS (gcd(11,32)=1 -> conflict-free)
}

// One row. o[0..9] = {d0,d1,t0,t1,t2,q0..q3,mean_phase}
// NOTE: D-path numerics (sinf/cosf/atan2f) must stay EXACTLY as the passing
// version (absmax margin 0.043/0.0628 depends on this). T/Q use __sinf: their
// sin contributions are scaled by <=1e-3 into the output -> error ~1e-9.
__device__ __forceinline__ void row_compute(
    float e,
    float dz0, float dz1, float dp0, float dp1,
    float tz0, float tz1, float tz2,
    float tp0, float tp1, float tp2,
    const float* qzr, const float* qpr,
    const float* Tm, const float* Qm, float tqc,
    float* o)
{
    const float ex = EXT_SC * e;

    // ---- D module (master clock, unbounded). Precise trig: feeds atan2. ----
    const float dpn0 = dp0 + DT_OM_D;
    const float dpn1 = dp1 + DT_OM_D;
    const float s0 = sinf(dpn0), c0 = cosf(dpn0);
    const float s1 = sinf(dpn1), c1 = cosf(dpn1);
    const float mp = atan2f(0.5f * (s0 + s1), 0.5f * (c0 + c1));

    o[0] = dz0 + DTf * (DRIVE * s0 + COUPLE * (dz1 + ex) - DAMP * dz0);
    o[1] = dz1 + DTf * (DRIVE * s1 + COUPLE * (dz0 + ex) - DAMP * dz1);

    // ---- T module: coupling matvec + entrainment toward mp, clamp GAMMA ----
    const float tzr[3] = {tz0, tz1, tz2};
    const float tpr[3] = {tp0, tp1, tp2};
    float to[3];
#pragma unroll
    for (int i = 0; i < 3; ++i) {
        const float nb = Tm[3 * i + 0] * tzr[0] + Tm[3 * i + 1] * tzr[1]
                       + Tm[3 * i + 2] * tzr[2] + ex;
        const float pn = tpr[i] + (DT_OM_T + ENTRAIN * __sinf(mp - tpr[i]));
        float v = tzr[i] + DTf * (DRIVE * __sinf(pn) + COUPLE * nb - DAMP * tzr[i]);
        v = fminf(fmaxf(v, -GAMMA_F), GAMMA_F);
        to[i] = v;
        o[2 + i] = v;
    }

    // ---- Q module: driven by mean T output * tq_coupling ----
    const float exq = EXT_SC * ((to[0] + to[1] + to[2]) * (1.0f / 3.0f) * tqc);
#pragma unroll
    for (int i = 0; i < 4; ++i) {
        const float nb = Qm[4 * i + 0] * qzr[0] + Qm[4 * i + 1] * qzr[1]
                       + Qm[4 * i + 2] * qzr[2] + Qm[4 * i + 3] * qzr[3] + exq;
        const float pn = qpr[i] + (DT_OM_Q + ENTRAIN * __sinf(mp - qpr[i]));
        float v = qzr[i] + DTf * (DRIVE * __sinf(pn) + COUPLE * nb - DAMP * qzr[i]);
        v = fminf(fmaxf(v, -GAMMA_F), GAMMA_F);
        o[5 + i] = v;
    }

    o[9] = mp;
}

__global__ __launch_bounds__(BLOCK) void genesis_kernel(
    const float* __restrict__ ext,
    const float* __restrict__ dz,
    const float* __restrict__ dp,
    const float* __restrict__ tz,
    const float* __restrict__ tp,
    const float* __restrict__ qz,
    const float* __restrict__ qp,
    const float* __restrict__ tcm,
    const float* __restrict__ qcm,
    const float* __restrict__ tqs,
    float* __restrict__ out,
    int B)
{
    __shared__ float so[BLOCK * OPAD];   // 11,264 B -> LDS never the occupancy limit

    const int t    = threadIdx.x;
    const int base = blockIdx.x * BLOCK;
    const int b    = base + t;           // this thread's row

    // wave-uniform tiny matrices -> compiler scalarizes to s_load
    float Tm[9], Qm[16];
#pragma unroll
    for (int i = 0; i < 9; ++i) Tm[i] = tcm[i];
#pragma unroll
    for (int i = 0; i < 16; ++i) Qm[i] = qcm[i];
    const float tqc = tqs[0];

    if (b < B) {
        // fully-coalesced direct loads (1 row/thread => lane-contiguous)
        const float  e   = ext[b];
        const float2 dzv = ((const float2*)dz)[b];
        const float2 dpv = ((const float2*)dp)[b];
        const float  t0  = tz[3 * b + 0], t1 = tz[3 * b + 1], t2 = tz[3 * b + 2];
        const float  p0  = tp[3 * b + 0], p1 = tp[3 * b + 1], p2 = tp[3 * b + 2];
        const float4 qzv = ((const float4*)qz)[b];
        const float4 qpv = ((const float4*)qp)[b];
        const float qzr[4] = {qzv.x, qzv.y, qzv.z, qzv.w};
        const float qpr[4] = {qpv.x, qpv.y, qpv.z, qpv.w};

        float o[10];
        row_compute(e, dzv.x, dzv.y, dpv.x, dpv.y,
                    t0, t1, t2, p0, p1, p2, qzr, qpr, Tm, Qm, tqc, o);

        // stage to LDS at stride-11 floats: banks (11*t) % 32 -> conflict-free
#pragma unroll
        for (int k = 0; k < 10; ++k) so[OPAD * t + k] = o[k];
    }
    __syncthreads();

    // cooperative, fully-coalesced float4 store of this block's 256 rows
    const int rows = min(BLOCK, B - base);
    if (rows == BLOCK) {
        float* outBase = out + (size_t)base * 10;   // 16B-aligned (base%256==0)
        constexpr int NF4 = BLOCK * 10 / 4;         // 640 float4 per block
#pragma unroll
        for (int c = t; c < NF4; c += BLOCK) {
            const int e0 = 4 * c;
            float4 v;
            v.x = so[OPAD * ((e0 + 0) / 10) + (e0 + 0) % 10];
            v.y = so[OPAD * ((e0 + 1) / 10) + (e0 + 1) % 10];
            v.z = so[OPAD * ((e0 + 2) / 10) + (e0 + 2) % 10];
            v.w = so[OPAD * ((e0 + 3) / 10) + (e0 + 3) % 10];
            ((float4*)outBase)[c] = v;
        }
    } else if (rows > 0) {
        // generic tail block: scalar coalesced
        const int nf = rows * 10;
        for (int k = t; k < nf; k += BLOCK) {
            out[(size_t)base * 10 + k] = so[OPAD * (k / 10) + (k % 10)];
        }
    }
}

extern "C" void kernel_launch(void* const* d_in, const int* in_sizes, int n_in,
                              void* d_out, int out_size, void* d_ws, size_t ws_size,
                              hipStream_t stream)
{
    const float* ext = (const float*)d_in[0];
    const float* dz  = (const float*)d_in[1];
    const float* dp  = (const float*)d_in[2];
    const float* tz  = (const float*)d_in[3];
    const float* tp  = (const float*)d_in[4];
    const float* qz  = (const float*)d_in[5];
    const float* qp  = (const float*)d_in[6];
    const float* tcm = (const float*)d_in[7];
    const float* qcm = (const float*)d_in[8];
    const float* tqs = (const float*)d_in[9];

    const int B = in_sizes[0];
    int grid = (B + BLOCK - 1) / BLOCK;
    if (grid < 1) grid = 1;

    genesis_kernel<<<grid, BLOCK, 0, stream>>>(ext, dz, dp, tz, tp, qz, qp,
                                               tcm, qcm, tqs,
                                               (float*)d_out, B);
}

// Round 4
// 75.112 us; speedup vs baseline: 1.3977x; 1.1866x over previous
//
#include <hip/hip_runtime.h>
#include <math.h>

// ---------------- constants (match reference, f32-cast like np.float32) -----
namespace {
constexpr float DTf     = 0.01f;
constexpr float GAMMA_F = 0.103f;
constexpr float DRIVE   = 0.1f;
constexpr float COUPLE  = 0.1f;
constexpr float DAMP    = 0.01f;
constexpr float ENTRAIN = 0.1f;
constexpr float EXT_SC  = 0.1f;

constexpr double PHI    = 1.618033988749895;
constexpr double TWO_PI = 6.283185307179586476925287;
constexpr double PHI2   = PHI * PHI;
constexpr double PHI4   = PHI2 * PHI2;
constexpr double PHI5   = PHI4 * PHI;
constexpr double PHI7   = PHI5 * PHI2;
constexpr double PHI11  = PHI7 * PHI4;

constexpr float OMEGA_D = (float)(TWO_PI / (40.0 * PHI11));
constexpr float OMEGA_T = (float)(TWO_PI / (40.0 * PHI7));
constexpr float OMEGA_Q = (float)(TWO_PI / (40.0 * PHI5));
constexpr float DT_OM_D = DTf * OMEGA_D;
constexpr float DT_OM_T = DTf * OMEGA_T;
constexpr float DT_OM_Q = DTf * OMEGA_Q;

constexpr int BLOCK = 256;
constexpr int RPT   = 2;                 // rows per thread
constexpr int RPB   = BLOCK * RPT;       // 512 rows per block
constexpr int PPAD  = 21;                // LDS floats per 2-row pair (20 + 1 pad), gcd(21,32)=1

typedef float f32x4 __attribute__((ext_vector_type(4)));  // clang vector: ok for nontemporal builtin
}

// One row. o[0..9] = {d0,d1,t0,t1,t2,q0..q3,mean_phase}
// NOTE: D-path numerics (sinf/cosf/atan2f) must stay EXACTLY as the passing
// version (absmax 0.0430 vs threshold 0.0628 depends on it). T/Q use __sinf:
// their sin contributions are scaled by <=1e-3 into the output.
__device__ __forceinline__ void row_compute(
    float e,
    float dz0, float dz1, float dp0, float dp1,
    const float* tzr, const float* tpr,
    const float* qzr, const float* qpr,
    const float* Tm, const float* Qm, float tqc,
    float* o)
{
    const float ex = EXT_SC * e;

    // ---- D module (master clock, unbounded). Precise trig: feeds atan2. ----
    const float dpn0 = dp0 + DT_OM_D;
    const float dpn1 = dp1 + DT_OM_D;
    const float s0 = sinf(dpn0), c0 = cosf(dpn0);
    const float s1 = sinf(dpn1), c1 = cosf(dpn1);
    const float mp = atan2f(0.5f * (s0 + s1), 0.5f * (c0 + c1));

    o[0] = dz0 + DTf * (DRIVE * s0 + COUPLE * (dz1 + ex) - DAMP * dz0);
    o[1] = dz1 + DTf * (DRIVE * s1 + COUPLE * (dz0 + ex) - DAMP * dz1);

    // ---- T module ----
    float to[3];
#pragma unroll
    for (int i = 0; i < 3; ++i) {
        const float nb = Tm[3 * i + 0] * tzr[0] + Tm[3 * i + 1] * tzr[1]
                       + Tm[3 * i + 2] * tzr[2] + ex;
        const float pn = tpr[i] + (DT_OM_T + ENTRAIN * __sinf(mp - tpr[i]));
        float v = tzr[i] + DTf * (DRIVE * __sinf(pn) + COUPLE * nb - DAMP * tzr[i]);
        v = fminf(fmaxf(v, -GAMMA_F), GAMMA_F);
        to[i] = v;
        o[2 + i] = v;
    }

    // ---- Q module ----
    const float exq = EXT_SC * ((to[0] + to[1] + to[2]) * (1.0f / 3.0f) * tqc);
#pragma unroll
    for (int i = 0; i < 4; ++i) {
        const float nb = Qm[4 * i + 0] * qzr[0] + Qm[4 * i + 1] * qzr[1]
                       + Qm[4 * i + 2] * qzr[2] + Qm[4 * i + 3] * qzr[3] + exq;
        const float pn = qpr[i] + (DT_OM_Q + ENTRAIN * __sinf(mp - qpr[i]));
        float v = qzr[i] + DTf * (DRIVE * __sinf(pn) + COUPLE * nb - DAMP * qzr[i]);
        v = fminf(fmaxf(v, -GAMMA_F), GAMMA_F);
        o[5 + i] = v;
    }

    o[9] = mp;
}

__global__ __launch_bounds__(BLOCK) void genesis_kernel(
    const float* __restrict__ ext,
    const float* __restrict__ dz,
    const float* __restrict__ dp,
    const float* __restrict__ tz,
    const float* __restrict__ tp,
    const float* __restrict__ qz,
    const float* __restrict__ qp,
    const float* __restrict__ tcm,
    const float* __restrict__ qcm,
    const float* __restrict__ tqs,
    float* __restrict__ out,
    int B)
{
    __shared__ float so[BLOCK * PPAD];   // 21.5 KB

    const int t    = threadIdx.x;
    const int base = blockIdx.x * RPB;   // first row of this block
    const int g    = blockIdx.x * BLOCK + t;   // this thread's row-PAIR index

    float Tm[9], Qm[16];
#pragma unroll
    for (int i = 0; i < 9; ++i) Tm[i] = tcm[i];
#pragma unroll
    for (int i = 0; i < 16; ++i) Qm[i] = qcm[i];
    const float tqc = tqs[0];

    const int rows = min(RPB, B - base); // rows valid in this block

    if (rows == RPB) {
        // ---------- full block: vectorized 2-rows-per-thread ----------
        const float2 ev  = ((const float2*)ext)[g];
        const float4 dzv = ((const float4*)dz)[g];
        const float4 dpv = ((const float4*)dp)[g];
        const float2* tz2 = (const float2*)(tz + 6 * (size_t)g);
        const float2* tp2 = (const float2*)(tp + 6 * (size_t)g);
        const float2 tza = tz2[0], tzb = tz2[1], tzc = tz2[2];
        const float2 tpa = tp2[0], tpb = tp2[1], tpc = tp2[2];
        const float4 qzA = ((const float4*)qz)[2 * g + 0];
        const float4 qzB = ((const float4*)qz)[2 * g + 1];
        const float4 qpA = ((const float4*)qp)[2 * g + 0];
        const float4 qpB = ((const float4*)qp)[2 * g + 1];

        const float tzrA[3] = {tza.x, tza.y, tzb.x};
        const float tzrB[3] = {tzb.y, tzc.x, tzc.y};
        const float tprA[3] = {tpa.x, tpa.y, tpb.x};
        const float tprB[3] = {tpb.y, tpc.x, tpc.y};
        const float qzrA[4] = {qzA.x, qzA.y, qzA.z, qzA.w};
        const float qzrB[4] = {qzB.x, qzB.y, qzB.z, qzB.w};
        const float qprA[4] = {qpA.x, qpA.y, qpA.z, qpA.w};
        const float qprB[4] = {qpB.x, qpB.y, qpB.z, qpB.w};

        float oA[10], oB[10];
        row_compute(ev.x, dzv.x, dzv.y, dpv.x, dpv.y,
                    tzrA, tprA, qzrA, qprA, Tm, Qm, tqc, oA);
        row_compute(ev.y, dzv.z, dzv.w, dpv.z, dpv.w,
                    tzrB, tprB, qzrB, qprB, Tm, Qm, tqc, oB);

#pragma unroll
        for (int k = 0; k < 10; ++k) so[PPAD * t + k]      = oA[k];
#pragma unroll
        for (int k = 0; k < 10; ++k) so[PPAD * t + 10 + k] = oB[k];

        __syncthreads();

        // cooperative, coalesced nontemporal float4 store (write-once data:
        // nt keeps the output from evicting inputs out of L3)
        f32x4* outV = (f32x4*)(out + (size_t)base * 10);   // 16B-aligned (base%512==0)
        constexpr int NF4 = RPB * 10 / 4;                  // 1280 float4 per block
#pragma unroll
        for (int c = t; c < NF4; c += BLOCK) {
            const int e0 = 4 * c;                  // e0%20 in {0,4,8,12,16}: never crosses pair
            const int lb = PPAD * (e0 / 20) + (e0 % 20);
            f32x4 v;
            v.x = so[lb + 0];
            v.y = so[lb + 1];
            v.z = so[lb + 2];
            v.w = so[lb + 3];
            __builtin_nontemporal_store(v, outV + c);
        }
    } else {
        // ---------- tail block: scalar per-row path ----------
#pragma unroll
        for (int r = 0; r < RPT; ++r) {
            const int lr = RPT * t + r;       // local row
            if (lr < rows) {
                const int b = base + lr;
                const float tzr[3] = {tz[3 * b], tz[3 * b + 1], tz[3 * b + 2]};
                const float tpr[3] = {tp[3 * b], tp[3 * b + 1], tp[3 * b + 2]};
                const float qzr[4] = {qz[4 * b], qz[4 * b + 1], qz[4 * b + 2], qz[4 * b + 3]};
                const float qpr[4] = {qp[4 * b], qp[4 * b + 1], qp[4 * b + 2], qp[4 * b + 3]};
                float o[10];
                row_compute(ext[b], dz[2 * b], dz[2 * b + 1], dp[2 * b], dp[2 * b + 1],
                            tzr, tpr, qzr, qpr, Tm, Qm, tqc, o);
                const int pairBase = PPAD * t + 10 * r;
                for (int k = 0; k < 10; ++k) so[pairBase + k] = o[k];
            }
        }
        __syncthreads();
        if (rows > 0) {
            const int nf = rows * 10;
            for (int k = t; k < nf; k += BLOCK) {
                out[(size_t)base * 10 + k] = so[PPAD * (k / 20) + (k % 20)];
            }
        }
    }
}

extern "C" void kernel_launch(void* const* d_in, const int* in_sizes, int n_in,
                              void* d_out, int out_size, void* d_ws, size_t ws_size,
                              hipStream_t stream)
{
    const float* ext = (const float*)d_in[0];
    const float* dz  = (const float*)d_in[1];
    const float* dp  = (const float*)d_in[2];
    const float* tz  = (const float*)d_in[3];
    const float* tp  = (const float*)d_in[4];
    const float* qz  = (const float*)d_in[5];
    const float* qp  = (const float*)d_in[6];
    const float* tcm = (const float*)d_in[7];
    const float* qcm = (const float*)d_in[8];
    const float* tqs = (const float*)d_in[9];

    const int B = in_sizes[0];
    int grid = (B + RPB - 1) / RPB;
    if (grid < 1) grid = 1;

    genesis_kernel<<<grid, BLOCK, 0, stream>>>(ext, dz, dp, tz, tp, qz, qp,
                                               tcm, qcm, tqs,
                                               (float*)d_out, B);
}